// Round 10
// baseline (405.269 us; speedup 1.0000x reference)
//
#include <hip/hip_runtime.h>
#include <math.h>

#define H 32
#define BSEG 16
#define CHUNKS 32

__device__ __forceinline__ float sigmoidf_(float x){ return 1.f/(1.f+expf(-x)); }

__device__ __forceinline__ unsigned int fenc(float f) {
    int i = __float_as_int(f);
    return (i >= 0) ? ((unsigned int)i | 0x80000000u) : ~(unsigned int)i;
}
__device__ __forceinline__ float fdec(unsigned int u) {
    int i = (u & 0x80000000u) ? (int)(u & 0x7FFFFFFFu) : (int)(~u);
    return __int_as_float(i);
}

// ---------------- prep: transposed GRU weights, fused biases, qvec, masked edge matrices, zero cnt ----------------
__global__ __launch_bounds__(512) void k_prep(
    const float* __restrict__ gru_wi, const float* __restrict__ gru_wh,
    const float* __restrict__ gru_bi, const float* __restrict__ gru_bh,
    const float* __restrict__ lstm_bi, const float* __restrict__ lstm_bh,
    const float* __restrict__ e1w, const float* __restrict__ e1b, const float* __restrict__ e2w,
    float* __restrict__ WI, float* __restrict__ WH, float* __restrict__ BS,
    float* __restrict__ MP, float* __restrict__ MM, int* __restrict__ flag,
    float* __restrict__ qvec, unsigned int* __restrict__ segmax,
    float* __restrict__ ssum, float* __restrict__ vsum,
    int* __restrict__ cnt, int N)
{
    int t = threadIdx.x;
    for (int i = t; i < N; i += 512) cnt[i] = 0;
    for (int idx = t; idx < 3072; idx += 512) {
        int k = idx >> 10, rem = idx & 1023, i = rem >> 5, o = rem & 31;
        WI[idx] = gru_wi[(k*32 + o)*32 + i];
        WH[idx] = gru_wh[(k*32 + o)*32 + i];
    }
    for (int idx = t; idx < 1024; idx += 512) {
        float mp = 0.f, mm = 0.f;
        #pragma unroll
        for (int k = 0; k < 8; ++k) {
            float w = e1w[k];
            float v = e2w[k*1024 + idx];
            if (w > 0.f) mp = fmaf(w, v, mp);
            if (w < 0.f) mm = fmaf(w, v, mm);
        }
        MP[idx] = mp;
        MM[idx] = mm;
    }
    if (t == 0) {
        int z = 1;
        for (int k = 0; k < 8; ++k) if (e1b[k] != 0.f) z = 0;
        flag[0] = z;
    }
    if (t < 32) {
        BS[t]      = gru_bi[t]      + gru_bh[t];
        BS[32 + t] = gru_bi[32 + t] + gru_bh[32 + t];
        BS[64 + t] = gru_bi[64 + t];
        BS[96 + t] = gru_bh[64 + t];
    }
    if (t < H) {
        float g0 = lstm_bi[t] + lstm_bh[t];
        float g2 = lstm_bi[2*H + t] + lstm_bh[2*H + t];
        float g3 = lstm_bi[3*H + t] + lstm_bh[3*H + t];
        float ig = sigmoidf_(g0);
        float gg = tanhf(g2);
        float og = sigmoidf_(g3);
        qvec[t] = og * tanhf(ig * gg);
    }
    for (int i = t; i < BSEG; i += 512) { segmax[i] = 0u; ssum[i] = 0.f; }
    for (int i = t; i < BSEG*H; i += 512) vsum[i] = 0.f;
}

// ---------------- CSR build: count -> scan -> scatter ----------------
__global__ __launch_bounds__(256) void k_count(const int* __restrict__ ei, int* __restrict__ cnt, int E)
{
    int e = blockIdx.x * 256 + threadIdx.x;
    if (e < E) atomicAdd(&cnt[ei[E + e]], 1);
}

__global__ __launch_bounds__(1024) void k_scan(
    const int* __restrict__ cnt, int* __restrict__ rowptr, int* __restrict__ cursor, int N)
{
    __shared__ int part[1024];
    int t = threadIdx.x;
    int chunk = (N + 1023) >> 10;
    int base = t * chunk;
    int s = 0;
    for (int i = 0; i < chunk; ++i) {
        int idx = base + i;
        if (idx < N) s += cnt[idx];
    }
    part[t] = s;
    __syncthreads();
    for (int off = 1; off < 1024; off <<= 1) {
        int add = (t >= off) ? part[t - off] : 0;
        __syncthreads();
        part[t] += add;
        __syncthreads();
    }
    int run = part[t] - s;                 // exclusive prefix for this chunk
    for (int i = 0; i < chunk; ++i) {
        int idx = base + i;
        if (idx < N) {
            rowptr[idx] = run;
            cursor[idx] = run;
            run += cnt[idx];
        }
    }
    if (t == 1023) rowptr[N] = part[1023];
}

__global__ __launch_bounds__(256) void k_scatter(
    const int* __restrict__ ei, const float* __restrict__ ea, int* __restrict__ cursor,
    int* __restrict__ esrc, float* __restrict__ eattr, int E)
{
    int e = blockIdx.x * 256 + threadIdx.x;
    if (e >= E) return;
    int dst = ei[E + e];
    int pos = atomicAdd(&cursor[dst], 1);
    esrc[pos] = ei[e];
    eattr[pos] = ea[e];
}

// ---- LDS-based K=32 passes (x row broadcast across node's 8 fg-lanes; weights across 8 node-lanes) ----
__device__ __forceinline__ void pass2_lds(const float* sm, int xb, int w0, int w1, int fg4,
                                          float a[4], float b[4])
{
    #pragma unroll 2
    for (int i4 = 0; i4 < 32; i4 += 4) {
        float4 xv  = *(const float4*)&sm[xb + i4];
        float4 w00 = *(const float4*)&sm[w0 + (i4+0)*32 + fg4];
        float4 w01 = *(const float4*)&sm[w0 + (i4+1)*32 + fg4];
        float4 w02 = *(const float4*)&sm[w0 + (i4+2)*32 + fg4];
        float4 w03 = *(const float4*)&sm[w0 + (i4+3)*32 + fg4];
        float4 w10 = *(const float4*)&sm[w1 + (i4+0)*32 + fg4];
        float4 w11 = *(const float4*)&sm[w1 + (i4+1)*32 + fg4];
        float4 w12 = *(const float4*)&sm[w1 + (i4+2)*32 + fg4];
        float4 w13 = *(const float4*)&sm[w1 + (i4+3)*32 + fg4];
        a[0]=fmaf(xv.x,w00.x,a[0]); a[1]=fmaf(xv.x,w00.y,a[1]); a[2]=fmaf(xv.x,w00.z,a[2]); a[3]=fmaf(xv.x,w00.w,a[3]);
        a[0]=fmaf(xv.y,w01.x,a[0]); a[1]=fmaf(xv.y,w01.y,a[1]); a[2]=fmaf(xv.y,w01.z,a[2]); a[3]=fmaf(xv.y,w01.w,a[3]);
        a[0]=fmaf(xv.z,w02.x,a[0]); a[1]=fmaf(xv.z,w02.y,a[1]); a[2]=fmaf(xv.z,w02.z,a[2]); a[3]=fmaf(xv.z,w02.w,a[3]);
        a[0]=fmaf(xv.w,w03.x,a[0]); a[1]=fmaf(xv.w,w03.y,a[1]); a[2]=fmaf(xv.w,w03.z,a[2]); a[3]=fmaf(xv.w,w03.w,a[3]);
        b[0]=fmaf(xv.x,w10.x,b[0]); b[1]=fmaf(xv.x,w10.y,b[1]); b[2]=fmaf(xv.x,w10.z,b[2]); b[3]=fmaf(xv.x,w10.w,b[3]);
        b[0]=fmaf(xv.y,w11.x,b[0]); b[1]=fmaf(xv.y,w11.y,b[1]); b[2]=fmaf(xv.y,w11.z,b[2]); b[3]=fmaf(xv.y,w11.w,b[3]);
        b[0]=fmaf(xv.z,w12.x,b[0]); b[1]=fmaf(xv.z,w12.y,b[1]); b[2]=fmaf(xv.z,w12.z,b[2]); b[3]=fmaf(xv.z,w12.w,b[3]);
        b[0]=fmaf(xv.w,w13.x,b[0]); b[1]=fmaf(xv.w,w13.y,b[1]); b[2]=fmaf(xv.w,w13.z,b[2]); b[3]=fmaf(xv.w,w13.w,b[3]);
    }
}

__device__ __forceinline__ void pass1_lds(const float* sm, int xb, int w0, int fg4, float a[4])
{
    #pragma unroll 2
    for (int i4 = 0; i4 < 32; i4 += 4) {
        float4 xv  = *(const float4*)&sm[xb + i4];
        float4 w00 = *(const float4*)&sm[w0 + (i4+0)*32 + fg4];
        float4 w01 = *(const float4*)&sm[w0 + (i4+1)*32 + fg4];
        float4 w02 = *(const float4*)&sm[w0 + (i4+2)*32 + fg4];
        float4 w03 = *(const float4*)&sm[w0 + (i4+3)*32 + fg4];
        a[0]=fmaf(xv.x,w00.x,a[0]); a[1]=fmaf(xv.x,w00.y,a[1]); a[2]=fmaf(xv.x,w00.z,a[2]); a[3]=fmaf(xv.x,w00.w,a[3]);
        a[0]=fmaf(xv.y,w01.x,a[0]); a[1]=fmaf(xv.y,w01.y,a[1]); a[2]=fmaf(xv.y,w01.z,a[2]); a[3]=fmaf(xv.y,w01.w,a[3]);
        a[0]=fmaf(xv.z,w02.x,a[0]); a[1]=fmaf(xv.z,w02.y,a[1]); a[2]=fmaf(xv.z,w02.z,a[2]); a[3]=fmaf(xv.z,w02.w,a[3]);
        a[0]=fmaf(xv.w,w03.x,a[0]); a[1]=fmaf(xv.w,w03.y,a[1]); a[2]=fmaf(xv.w,w03.z,a[2]); a[3]=fmaf(xv.w,w03.w,a[3]);
    }
}

// ---------------- tab: proj fused + initial table. fast: T[n] stride 96; fallback: G[n] stride 288 ----------------
#define TW 3072
__global__ __launch_bounds__(256, 2) void k_tab(
    const float* __restrict__ x, const float* __restrict__ proj_w, const float* __restrict__ proj_b,
    const float* __restrict__ e2w, const float* __restrict__ e2b,
    const float* __restrict__ MP, const float* __restrict__ MM, const int* __restrict__ flag,
    float* __restrict__ h, float* __restrict__ A, int N)
{
    __shared__ float sm[TW + 4*288];
    int tid = threadIdx.x;
    int lane = tid & 63;
    int w = tid >> 6;
    int fg = lane & 7, fg4 = fg*4;
    int nw = lane >> 3;
    int n = (blockIdx.x * 4 + w) * 8 + nw;
    bool valid = (n < N);
    int nc = valid ? n : (N - 1);
    int xb = TW + w*288 + nw*36;

    // proj fused: h row for this node
    {
        float4 xv = *(const float4*)&x[nc*4];
        float r_[4];
        #pragma unroll
        for (int j = 0; j < 4; ++j) {
            int o = fg4 + j;
            float a = proj_b[o];
            a = fmaf(xv.x, proj_w[0*32 + o], a);
            a = fmaf(xv.y, proj_w[1*32 + o], a);
            a = fmaf(xv.z, proj_w[2*32 + o], a);
            a = fmaf(xv.w, proj_w[3*32 + o], a);
            r_[j] = fmaxf(a, 0.f);
        }
        if (valid) *(float4*)&h[n*32 + fg4] = make_float4(r_[0], r_[1], r_[2], r_[3]);
        *(float4*)&sm[xb + fg4] = make_float4(r_[0], r_[1], r_[2], r_[3]);
    }

    if (flag[0]) {
        float4* s4 = (float4*)sm;
        for (int i = tid; i < 768; i += 256) {
            const float4* src = (i < 256) ? (const float4*)MP
                              : (i < 512) ? (const float4*)MM
                                          : (const float4*)e2b;
            s4[i] = src[i & 255];
        }
        __syncthreads();
        #pragma unroll 1
        for (int cc = 0; cc < 3; ++cc) {
            float acc[4] = {0.f, 0.f, 0.f, 0.f};
            pass1_lds(sm, xb, cc*1024, fg4, acc);
            if (valid)
                *(float4*)&A[(size_t)n*96 + cc*32 + fg4] =
                    make_float4(acc[0], acc[1], acc[2], acc[3]);
        }
    } else {
        #pragma unroll 1
        for (int cg = 0; cg < 3; ++cg) {
            __syncthreads();
            float4* s4 = (float4*)sm;
            for (int i = tid; i < 768; i += 256) {
                int c = cg*3 + (i >> 8);
                const float4* src = (c < 8) ? (const float4*)(e2w + (size_t)c*1024)
                                            : (const float4*)e2b;
                s4[i] = src[i & 255];
            }
            __syncthreads();
            #pragma unroll 1
            for (int cc = 0; cc < 3; ++cc) {
                float acc[4] = {0.f, 0.f, 0.f, 0.f};
                pass1_lds(sm, xb, cc*1024, fg4, acc);
                if (valid)
                    *(float4*)&A[(size_t)n*288 + (cg*3+cc)*32 + fg4] =
                        make_float4(acc[0], acc[1], acc[2], acc[3]);
            }
        }
    }
}

// ---------------- agg: one WAVE per node; 8 edge-slots x 8 fg lanes; no LDS, no atomics ----------------
__global__ __launch_bounds__(256) void k_agg(
    const int* __restrict__ rowptr, const int* __restrict__ esrc, const float* __restrict__ eattr,
    const float* __restrict__ T, const int* __restrict__ flag,
    const float* __restrict__ e1w, const float* __restrict__ e1b,
    float* __restrict__ agg, int N)
{
    int n = blockIdx.x * 4 + (threadIdx.x >> 6);
    if (n >= N) return;                       // wave-uniform exit
    int lane = threadIdx.x & 63;
    int slot = lane >> 3;
    int fg4 = (lane & 7) * 4;
    int beg = rowptr[n];
    int end = rowptr[n + 1];

    float a0 = 0.f, a1 = 0.f, a2 = 0.f, a3 = 0.f;
    if (flag[0]) {
        for (int j = beg + slot; j < end; j += 8) {
            int src = esrc[j];
            float a = eattr[j];
            const float* base = T + (size_t)src * 96;
            float4 p = *(const float4*)&base[(a > 0.f ? 0 : 32) + fg4];
            float4 b = *(const float4*)&base[64 + fg4];
            a0 += fmaf(a, p.x, b.x);
            a1 += fmaf(a, p.y, b.y);
            a2 += fmaf(a, p.z, b.z);
            a3 += fmaf(a, p.w, b.w);
        }
    } else {
        for (int j = beg + slot; j < end; j += 8) {
            int src = esrc[j];
            float a = eattr[j];
            const float* Gp = T + (size_t)src * 288;
            float4 b = *(const float4*)&Gp[256 + fg4];
            float m0 = b.x, m1 = b.y, m2 = b.z, m3 = b.w;
            #pragma unroll
            for (int k = 0; k < 8; ++k) {
                float t = fmaxf(fmaf(a, e1w[k], e1b[k]), 0.f);
                float4 g = *(const float4*)&Gp[k*32 + fg4];
                m0 = fmaf(t, g.x, m0); m1 = fmaf(t, g.y, m1);
                m2 = fmaf(t, g.z, m2); m3 = fmaf(t, g.w, m3);
            }
            a0 += m0; a1 += m1; a2 += m2; a3 += m3;
        }
    }
    // reduce across the 8 slots (lane bits 3..5)
    #pragma unroll
    for (int m = 8; m <= 32; m <<= 1) {
        a0 += __shfl_xor(a0, m, 64);
        a1 += __shfl_xor(a1, m, 64);
        a2 += __shfl_xor(a2, m, 64);
        a3 += __shfl_xor(a3, m, 64);
    }
    if (slot == 0)
        *(float4*)&agg[(size_t)n*32 + fg4] = make_float4(a0, a1, a2, a3);
}

// ---------------- GRU node update: GEMVs in LDS; reads agg; optional next-table; optional e=h·q ----------------
// LDS floats: ROOT[0,1024) WH[1024,4096) WI[4096,7168) MW[7168,10240) X[10240,+1152)
#define XGR 10240
__global__ __launch_bounds__(256, 2) void k_gru(
    float* __restrict__ h, const float* __restrict__ agg, const int* __restrict__ flag,
    const float* __restrict__ root_w, const float* __restrict__ conv_b,
    const float* __restrict__ WI, const float* __restrict__ WH, const float* __restrict__ BS,
    const float* __restrict__ MP, const float* __restrict__ MM,
    const float* __restrict__ e2b, const float* __restrict__ e2w,
    const float* __restrict__ qvec, const int* __restrict__ batch,
    float* __restrict__ ebuf, unsigned int* __restrict__ segmax,
    float* __restrict__ TOUT, int N, int computeT, int computeE)
{
    __shared__ float sm[XGR + 4*288];
    int tid = threadIdx.x;
    int fast = flag[0];
    {
        float4* s4 = (float4*)sm;
        const float4* r4  = (const float4*)root_w;
        const float4* wh4 = (const float4*)WH;
        const float4* wi4 = (const float4*)WI;
        for (int i = tid; i < 256; i += 256) s4[i] = r4[i];
        for (int i = tid; i < 768; i += 256) s4[256  + i] = wh4[i];
        for (int i = tid; i < 768; i += 256) s4[1024 + i] = wi4[i];
        if (computeT && fast) {
            for (int i = tid; i < 768; i += 256) {
                const float4* src = (i < 256) ? (const float4*)MP
                                  : (i < 512) ? (const float4*)MM
                                              : (const float4*)e2b;
                s4[1792 + i] = src[i & 255];
            }
        }
    }
    __syncthreads();

    int lane = tid & 63;
    int w = tid >> 6;
    int fg = lane & 7, fg4 = fg*4;
    int nw = lane >> 3;
    int n = (blockIdx.x * 4 + w) * 8 + nw;
    bool valid = (n < N);
    int nc = valid ? n : (N - 1);
    int xb = XGR + w*288 + nw*36;

    float4 hv4 = *(const float4*)&h[nc*32 + fg4];
    float hold[4] = {hv4.x, hv4.y, hv4.z, hv4.w};
    *(float4*)&sm[xb + fg4] = hv4;        // publish h row (wave-local)

    float outv[4], gh2[4];
    {
        float4 av4 = *(const float4*)&agg[(size_t)nc*32 + fg4];
        float4 cb4 = *(const float4*)&conv_b[fg4];
        outv[0]=av4.x+cb4.x; outv[1]=av4.y+cb4.y; outv[2]=av4.z+cb4.z; outv[3]=av4.w+cb4.w;
        float4 b3 = *(const float4*)&BS[96 + fg4];
        gh2[0]=b3.x; gh2[1]=b3.y; gh2[2]=b3.z; gh2[3]=b3.w;
    }
    pass2_lds(sm, xb, 0, 1024 + 2048, fg4, outv, gh2);

    float gh0[4] = {0.f,0.f,0.f,0.f};
    float gh1[4] = {0.f,0.f,0.f,0.f};
    pass2_lds(sm, xb, 1024, 2048, fg4, gh0, gh1);

    float outr[4];
    #pragma unroll
    for (int j = 0; j < 4; ++j) outr[j] = fmaxf(outv[j], 0.f);

    *(float4*)&sm[xb + fg4] = make_float4(outr[0], outr[1], outr[2], outr[3]);

    float gi0[4], gi1[4], gi2[4];
    {
        float4 b0 = *(const float4*)&BS[fg4];
        float4 b1 = *(const float4*)&BS[32 + fg4];
        float4 b2 = *(const float4*)&BS[64 + fg4];
        gi0[0]=b0.x; gi0[1]=b0.y; gi0[2]=b0.z; gi0[3]=b0.w;
        gi1[0]=b1.x; gi1[1]=b1.y; gi1[2]=b1.z; gi1[3]=b1.w;
        gi2[0]=b2.x; gi2[1]=b2.y; gi2[2]=b2.z; gi2[3]=b2.w;
    }
    pass2_lds(sm, xb, 4096, 5120, fg4, gi0, gi1);
    pass1_lds(sm, xb, 6144, fg4, gi2);

    float hnew[4];
    #pragma unroll
    for (int j = 0; j < 4; ++j) {
        float r = sigmoidf_(gi0[j] + gh0[j]);
        float z = sigmoidf_(gi1[j] + gh1[j]);
        float nn = tanhf(gi2[j] + r * gh2[j]);
        hnew[j] = (1.f - z) * nn + z * hold[j];
    }
    if (valid) *(float4*)&h[n*32 + fg4] = make_float4(hnew[0], hnew[1], hnew[2], hnew[3]);

    // ---- fused readout pass1: e = h_new · q, segment max ----
    if (computeE) {
        float4 qv = *(const float4*)&qvec[fg4];
        float e = hnew[0]*qv.x + hnew[1]*qv.y + hnew[2]*qv.z + hnew[3]*qv.w;
        e += __shfl_xor(e, 1, 64);
        e += __shfl_xor(e, 2, 64);
        e += __shfl_xor(e, 4, 64);
        if (valid && fg == 0) {
            ebuf[n] = e;
            atomicMax(&segmax[batch[n]], fenc(e));
        }
    }

    // ---- next-iteration table into TOUT ----
    if (computeT) {
        *(float4*)&sm[xb + fg4] = make_float4(hnew[0], hnew[1], hnew[2], hnew[3]);
        if (fast) {
            #pragma unroll 1
            for (int cc = 0; cc < 3; ++cc) {
                float acc[4] = {0.f, 0.f, 0.f, 0.f};
                pass1_lds(sm, xb, 7168 + cc*1024, fg4, acc);
                if (valid)
                    *(float4*)&TOUT[(size_t)n*96 + cc*32 + fg4] =
                        make_float4(acc[0], acc[1], acc[2], acc[3]);
            }
        } else {
            #pragma unroll 1
            for (int cg = 0; cg < 3; ++cg) {
                __syncthreads();
                float4* s4 = (float4*)sm;
                for (int i = tid; i < 768; i += 256) {
                    int c = cg*3 + (i >> 8);
                    const float4* src = (c < 8) ? (const float4*)(e2w + (size_t)c*1024)
                                                : (const float4*)e2b;
                    s4[1792 + i] = src[i & 255];
                }
                __syncthreads();
                #pragma unroll 1
                for (int cc = 0; cc < 3; ++cc) {
                    float acc[4] = {0.f, 0.f, 0.f, 0.f};
                    pass1_lds(sm, xb, 7168 + cc*1024, fg4, acc);
                    if (valid)
                        *(float4*)&TOUT[(size_t)n*288 + (cg*3+cc)*32 + fg4] =
                            make_float4(acc[0], acc[1], acc[2], acc[3]);
                }
            }
        }
    }
}

// ---------------- readout pass2: a = exp(e - emax); vsum += a*h; ssum += a ----------------
__global__ __launch_bounds__(256) void k_pass2(
    const float* __restrict__ h, const int* __restrict__ batch,
    const float* __restrict__ ebuf, const unsigned int* __restrict__ segmax,
    float* __restrict__ ssum, float* __restrict__ vsum, int N)
{
    int b = blockIdx.x / CHUNKS;
    int c = blockIdx.x % CHUNKS;
    int lo = 0, hi = N;
    while (lo < hi) { int mid = (lo + hi) >> 1; if (batch[mid] < b) lo = mid + 1; else hi = mid; }
    int s = lo;
    lo = 0; hi = N;
    while (lo < hi) { int mid = (lo + hi) >> 1; if (batch[mid] < b + 1) lo = mid + 1; else hi = mid; }
    int e = lo;
    int len = e - s;
    int per = (len + CHUNKS - 1) / CHUNKS;
    int n0 = s + c * per;
    int n1 = min(n0 + per, e);

    int tid = threadIdx.x;
    int ln = tid >> 5, o = tid & 31;
    float emax = fdec(segmax[b]);
    float vacc = 0.f, sacc = 0.f;
    for (int nn = n0 + ln; nn < n1; nn += 8) {
        float a = expf(ebuf[nn] - emax);
        vacc += a * h[nn * H + o];
        if (o == 0) sacc += a;
    }
    __shared__ float vsh[8][H];
    __shared__ float ssh[8];
    vsh[ln][o] = vacc;
    if (o == 0) ssh[ln] = sacc;
    __syncthreads();
    if (tid < H) {
        float v = 0.f;
        #pragma unroll
        for (int g = 0; g < 8; ++g) v += vsh[g][tid];
        atomicAdd(&vsum[b * H + tid], v);
    } else if (tid == H) {
        float stot = 0.f;
        #pragma unroll
        for (int g = 0; g < 8; ++g) stot += ssh[g];
        atomicAdd(&ssum[b], stot);
    }
}

// ---------------- final MLP on (16, 64) ----------------
__global__ __launch_bounds__(512) void k_mlp(
    const float* __restrict__ qvec, const float* __restrict__ ssum, const float* __restrict__ vsum,
    const float* __restrict__ f1w, const float* __restrict__ f1b,
    const float* __restrict__ f2w, const float* __restrict__ f2b,
    const float* __restrict__ f3w, const float* __restrict__ f3b,
    float* __restrict__ out)
{
    __shared__ float qsm[BSEG][2 * H];
    __shared__ float o1[BSEG][H];
    __shared__ float o2[BSEG][H];
    int tid = threadIdx.x;
    int b = tid >> 5, j = tid & 31;
    float st = ssum[b];
    qsm[b][j] = qvec[j];
    qsm[b][H + j] = (st > 0.f) ? vsum[b * H + j] / st : 0.f;
    __syncthreads();
    float acc = f1b[j];
    for (int i = 0; i < 2 * H; ++i) acc += qsm[b][i] * f1w[i * H + j];
    o1[b][j] = fmaxf(acc, 0.f);
    __syncthreads();
    acc = f2b[j];
    for (int i = 0; i < H; ++i) acc += o1[b][i] * f2w[i * H + j];
    o2[b][j] = fmaxf(acc, 0.f);
    __syncthreads();
    float v = o2[b][j] * f3w[j];
    #pragma unroll
    for (int m = 16; m >= 1; m >>= 1) v += __shfl_xor(v, m);
    if (j == 0) out[b] = v + f3b[0];
}

extern "C" void kernel_launch(void* const* d_in, const int* in_sizes, int n_in,
                              void* d_out, int out_size, void* d_ws, size_t ws_size,
                              hipStream_t stream)
{
    const float* x      = (const float*)d_in[0];
    const int*   ei     = (const int*)d_in[1];
    const float* ea     = (const float*)d_in[2];
    const int*   batch  = (const int*)d_in[3];
    const float* proj_w = (const float*)d_in[4];
    const float* proj_b = (const float*)d_in[5];
    const float* e1w    = (const float*)d_in[6];
    const float* e1b    = (const float*)d_in[7];
    const float* e2w    = (const float*)d_in[8];
    const float* e2b    = (const float*)d_in[9];
    const float* root_w = (const float*)d_in[10];
    const float* conv_b = (const float*)d_in[11];
    const float* gru_wi = (const float*)d_in[12];
    const float* gru_wh = (const float*)d_in[13];
    const float* gru_bi = (const float*)d_in[14];
    const float* gru_bh = (const float*)d_in[15];
    const float* lstm_bi = (const float*)d_in[18];
    const float* lstm_bh = (const float*)d_in[19];
    const float* f1w    = (const float*)d_in[20];
    const float* f1b    = (const float*)d_in[21];
    const float* f2w    = (const float*)d_in[22];
    const float* f2b    = (const float*)d_in[23];
    const float* f3w    = (const float*)d_in[24];
    const float* f3b    = (const float*)d_in[25];

    const int N = in_sizes[0] / 4;
    const int E = in_sizes[2];

    float* ws   = (float*)d_ws;
    float* h    = ws;                        // N*32
    float* A    = h + (size_t)N * H;         // N*288 (ping)
    float* Bb   = A + (size_t)N * 288;       // N*288 (pong)
    float* agg  = Bb + (size_t)N * 288;      // N*32
    float* ebuf = agg + (size_t)N * H;       // N
    float* qvec = ebuf + N;                  // 32
    unsigned int* segmax = (unsigned int*)(qvec + H);  // 16
    float* ssum = (float*)(segmax + BSEG);   // 16
    float* vsum = ssum + BSEG;               // 512
    float* WI   = vsum + BSEG * H;           // 3072
    float* WH   = WI + 3072;                 // 3072
    float* BS   = WH + 3072;                 // 128
    float* MP   = BS + 128;                  // 1024
    float* MM   = MP + 1024;                 // 1024
    int*   flag = (int*)(MM + 1024);         // 1
    int*   cnt    = flag + 1;                // N
    int*   rowptr = cnt + N;                 // N+1
    int*   cursor = rowptr + N + 1;          // N
    int*   esrc   = cursor + N;              // E
    float* eattr  = (float*)(esrc + E);      // E

    const int nwaves = (N + 7) / 8;          // 8 nodes per wave (gru/tab)
    const int nb4 = (nwaves + 3) / 4;        // 4 waves per block
    const int ablocks = (N + 3) / 4;         // 1 wave per node (agg)
    const int cblocks = (E + 255) / 256;

    k_prep<<<1, 512, 0, stream>>>(gru_wi, gru_wh, gru_bi, gru_bh, lstm_bi, lstm_bh,
                                  e1w, e1b, e2w,
                                  WI, WH, BS, MP, MM, flag, qvec, segmax, ssum, vsum, cnt, N);
    k_count<<<cblocks, 256, 0, stream>>>(ei, cnt, E);
    k_scan<<<1, 1024, 0, stream>>>(cnt, rowptr, cursor, N);
    k_scatter<<<cblocks, 256, 0, stream>>>(ei, ea, cursor, esrc, eattr, E);
    k_tab<<<nb4, 256, 0, stream>>>(x, proj_w, proj_b, e2w, e2b, MP, MM, flag, h, A, N);

    k_agg<<<ablocks, 256, 0, stream>>>(rowptr, esrc, eattr, A, flag, e1w, e1b, agg, N);
    k_gru<<<nb4, 256, 0, stream>>>(h, agg, flag, root_w, conv_b, WI, WH, BS, MP, MM,
                                   e2b, e2w, qvec, batch, ebuf, segmax, Bb, N, 1, 0);
    k_agg<<<ablocks, 256, 0, stream>>>(rowptr, esrc, eattr, Bb, flag, e1w, e1b, agg, N);
    k_gru<<<nb4, 256, 0, stream>>>(h, agg, flag, root_w, conv_b, WI, WH, BS, MP, MM,
                                   e2b, e2w, qvec, batch, ebuf, segmax, A, N, 1, 0);
    k_agg<<<ablocks, 256, 0, stream>>>(rowptr, esrc, eattr, A, flag, e1w, e1b, agg, N);
    k_gru<<<nb4, 256, 0, stream>>>(h, agg, flag, root_w, conv_b, WI, WH, BS, MP, MM,
                                   e2b, e2w, qvec, batch, ebuf, segmax, Bb, N, 0, 1);

    k_pass2<<<BSEG * CHUNKS, 256, 0, stream>>>(h, batch, ebuf, segmax, ssum, vsum, N);
    k_mlp<<<1, 512, 0, stream>>>(qvec, ssum, vsum, f1w, f1b, f2w, f2b, f3w, f3b, (float*)d_out);
}

// Round 11
// 396.678 us; speedup vs baseline: 1.0217x; 1.0217x over previous
//
#include <hip/hip_runtime.h>
#include <math.h>

#define H 32
#define BSEG 16
#define CHUNKS 32

__device__ __forceinline__ float sigmoidf_(float x){ return 1.f/(1.f+expf(-x)); }

__device__ __forceinline__ unsigned int fenc(float f) {
    int i = __float_as_int(f);
    return (i >= 0) ? ((unsigned int)i | 0x80000000u) : ~(unsigned int)i;
}
__device__ __forceinline__ float fdec(unsigned int u) {
    int i = (u & 0x80000000u) ? (int)(u & 0x7FFFFFFFu) : (int)(~u);
    return __int_as_float(i);
}

// ---------------- prep: transposed GRU weights, fused biases, qvec, masked edge matrices, zero cnt ----------------
__global__ __launch_bounds__(512) void k_prep(
    const float* __restrict__ gru_wi, const float* __restrict__ gru_wh,
    const float* __restrict__ gru_bi, const float* __restrict__ gru_bh,
    const float* __restrict__ lstm_bi, const float* __restrict__ lstm_bh,
    const float* __restrict__ e1w, const float* __restrict__ e1b, const float* __restrict__ e2w,
    float* __restrict__ WI, float* __restrict__ WH, float* __restrict__ BS,
    float* __restrict__ MP, float* __restrict__ MM, int* __restrict__ flag,
    float* __restrict__ qvec, unsigned int* __restrict__ segmax,
    float* __restrict__ ssum, float* __restrict__ vsum,
    int* __restrict__ cnt, int N)
{
    int t = threadIdx.x;
    for (int i = t; i < N; i += 512) cnt[i] = 0;
    for (int idx = t; idx < 3072; idx += 512) {
        int k = idx >> 10, rem = idx & 1023, i = rem >> 5, o = rem & 31;
        WI[idx] = gru_wi[(k*32 + o)*32 + i];
        WH[idx] = gru_wh[(k*32 + o)*32 + i];
    }
    for (int idx = t; idx < 1024; idx += 512) {
        float mp = 0.f, mm = 0.f;
        #pragma unroll
        for (int k = 0; k < 8; ++k) {
            float w = e1w[k];
            float v = e2w[k*1024 + idx];
            if (w > 0.f) mp = fmaf(w, v, mp);
            if (w < 0.f) mm = fmaf(w, v, mm);
        }
        MP[idx] = mp;
        MM[idx] = mm;
    }
    if (t == 0) {
        int z = 1;
        for (int k = 0; k < 8; ++k) if (e1b[k] != 0.f) z = 0;
        flag[0] = z;
    }
    if (t < 32) {
        BS[t]      = gru_bi[t]      + gru_bh[t];
        BS[32 + t] = gru_bi[32 + t] + gru_bh[32 + t];
        BS[64 + t] = gru_bi[64 + t];
        BS[96 + t] = gru_bh[64 + t];
    }
    if (t < H) {
        float g0 = lstm_bi[t] + lstm_bh[t];
        float g2 = lstm_bi[2*H + t] + lstm_bh[2*H + t];
        float g3 = lstm_bi[3*H + t] + lstm_bh[3*H + t];
        float ig = sigmoidf_(g0);
        float gg = tanhf(g2);
        float og = sigmoidf_(g3);
        qvec[t] = og * tanhf(ig * gg);
    }
    for (int i = t; i < BSEG; i += 512) { segmax[i] = 0u; ssum[i] = 0.f; }
    for (int i = t; i < BSEG*H; i += 512) vsum[i] = 0.f;
}

// ---------------- CSR build: count -> scan -> scatter ----------------
__global__ __launch_bounds__(256) void k_count(const int* __restrict__ ei, int* __restrict__ cnt, int E)
{
    int e = blockIdx.x * 256 + threadIdx.x;
    if (e < E) atomicAdd(&cnt[ei[E + e]], 1);
}

__global__ __launch_bounds__(1024) void k_scan(
    const int* __restrict__ cnt, int* __restrict__ rowptr, int* __restrict__ cursor, int N)
{
    __shared__ int part[1024];
    int t = threadIdx.x;
    int chunk = (N + 1023) >> 10;
    int base = t * chunk;
    int s = 0;
    for (int i = 0; i < chunk; ++i) {
        int idx = base + i;
        if (idx < N) s += cnt[idx];
    }
    part[t] = s;
    __syncthreads();
    for (int off = 1; off < 1024; off <<= 1) {
        int add = (t >= off) ? part[t - off] : 0;
        __syncthreads();
        part[t] += add;
        __syncthreads();
    }
    int run = part[t] - s;                 // exclusive prefix for this chunk
    for (int i = 0; i < chunk; ++i) {
        int idx = base + i;
        if (idx < N) {
            rowptr[idx] = run;
            cursor[idx] = run;
            run += cnt[idx];
        }
    }
    if (t == 1023) rowptr[N] = part[1023];
}

__global__ __launch_bounds__(256) void k_scatter(
    const int* __restrict__ ei, const float* __restrict__ ea, int* __restrict__ cursor,
    int* __restrict__ esrc, float* __restrict__ eattr, int E)
{
    int e = blockIdx.x * 256 + threadIdx.x;
    if (e >= E) return;
    int dst = ei[E + e];
    int pos = atomicAdd(&cursor[dst], 1);
    esrc[pos] = ei[e];
    eattr[pos] = ea[e];
}

// ---- LDS-based K=32 passes (x row broadcast across node's 8 fg-lanes; weights across 8 node-lanes) ----
__device__ __forceinline__ void pass2_lds(const float* sm, int xb, int w0, int w1, int fg4,
                                          float a[4], float b[4])
{
    #pragma unroll 2
    for (int i4 = 0; i4 < 32; i4 += 4) {
        float4 xv  = *(const float4*)&sm[xb + i4];
        float4 w00 = *(const float4*)&sm[w0 + (i4+0)*32 + fg4];
        float4 w01 = *(const float4*)&sm[w0 + (i4+1)*32 + fg4];
        float4 w02 = *(const float4*)&sm[w0 + (i4+2)*32 + fg4];
        float4 w03 = *(const float4*)&sm[w0 + (i4+3)*32 + fg4];
        float4 w10 = *(const float4*)&sm[w1 + (i4+0)*32 + fg4];
        float4 w11 = *(const float4*)&sm[w1 + (i4+1)*32 + fg4];
        float4 w12 = *(const float4*)&sm[w1 + (i4+2)*32 + fg4];
        float4 w13 = *(const float4*)&sm[w1 + (i4+3)*32 + fg4];
        a[0]=fmaf(xv.x,w00.x,a[0]); a[1]=fmaf(xv.x,w00.y,a[1]); a[2]=fmaf(xv.x,w00.z,a[2]); a[3]=fmaf(xv.x,w00.w,a[3]);
        a[0]=fmaf(xv.y,w01.x,a[0]); a[1]=fmaf(xv.y,w01.y,a[1]); a[2]=fmaf(xv.y,w01.z,a[2]); a[3]=fmaf(xv.y,w01.w,a[3]);
        a[0]=fmaf(xv.z,w02.x,a[0]); a[1]=fmaf(xv.z,w02.y,a[1]); a[2]=fmaf(xv.z,w02.z,a[2]); a[3]=fmaf(xv.z,w02.w,a[3]);
        a[0]=fmaf(xv.w,w03.x,a[0]); a[1]=fmaf(xv.w,w03.y,a[1]); a[2]=fmaf(xv.w,w03.z,a[2]); a[3]=fmaf(xv.w,w03.w,a[3]);
        b[0]=fmaf(xv.x,w10.x,b[0]); b[1]=fmaf(xv.x,w10.y,b[1]); b[2]=fmaf(xv.x,w10.z,b[2]); b[3]=fmaf(xv.x,w10.w,b[3]);
        b[0]=fmaf(xv.y,w11.x,b[0]); b[1]=fmaf(xv.y,w11.y,b[1]); b[2]=fmaf(xv.y,w11.z,b[2]); b[3]=fmaf(xv.y,w11.w,b[3]);
        b[0]=fmaf(xv.z,w12.x,b[0]); b[1]=fmaf(xv.z,w12.y,b[1]); b[2]=fmaf(xv.z,w12.z,b[2]); b[3]=fmaf(xv.z,w12.w,b[3]);
        b[0]=fmaf(xv.w,w13.x,b[0]); b[1]=fmaf(xv.w,w13.y,b[1]); b[2]=fmaf(xv.w,w13.z,b[2]); b[3]=fmaf(xv.w,w13.w,b[3]);
    }
}

__device__ __forceinline__ void pass1_lds(const float* sm, int xb, int w0, int fg4, float a[4])
{
    #pragma unroll 2
    for (int i4 = 0; i4 < 32; i4 += 4) {
        float4 xv  = *(const float4*)&sm[xb + i4];
        float4 w00 = *(const float4*)&sm[w0 + (i4+0)*32 + fg4];
        float4 w01 = *(const float4*)&sm[w0 + (i4+1)*32 + fg4];
        float4 w02 = *(const float4*)&sm[w0 + (i4+2)*32 + fg4];
        float4 w03 = *(const float4*)&sm[w0 + (i4+3)*32 + fg4];
        a[0]=fmaf(xv.x,w00.x,a[0]); a[1]=fmaf(xv.x,w00.y,a[1]); a[2]=fmaf(xv.x,w00.z,a[2]); a[3]=fmaf(xv.x,w00.w,a[3]);
        a[0]=fmaf(xv.y,w01.x,a[0]); a[1]=fmaf(xv.y,w01.y,a[1]); a[2]=fmaf(xv.y,w01.z,a[2]); a[3]=fmaf(xv.y,w01.w,a[3]);
        a[0]=fmaf(xv.z,w02.x,a[0]); a[1]=fmaf(xv.z,w02.y,a[1]); a[2]=fmaf(xv.z,w02.z,a[2]); a[3]=fmaf(xv.z,w02.w,a[3]);
        a[0]=fmaf(xv.w,w03.x,a[0]); a[1]=fmaf(xv.w,w03.y,a[1]); a[2]=fmaf(xv.w,w03.z,a[2]); a[3]=fmaf(xv.w,w03.w,a[3]);
    }
}

// ---------------- tab: proj fused + initial table. fast: T[n] stride 96; fallback: G[n] stride 288 ----------------
#define TW 3072
__global__ __launch_bounds__(256, 4) void k_tab(
    const float* __restrict__ x, const float* __restrict__ proj_w, const float* __restrict__ proj_b,
    const float* __restrict__ e2w, const float* __restrict__ e2b,
    const float* __restrict__ MP, const float* __restrict__ MM, const int* __restrict__ flag,
    float* __restrict__ h, float* __restrict__ A, int N)
{
    __shared__ float sm[TW + 4*288];
    int tid = threadIdx.x;
    int lane = tid & 63;
    int w = tid >> 6;
    int fg = lane & 7, fg4 = fg*4;
    int nw = lane >> 3;
    int n = (blockIdx.x * 4 + w) * 8 + nw;
    bool valid = (n < N);
    int nc = valid ? n : (N - 1);
    int xb = TW + w*288 + nw*36;

    // proj fused: h row for this node
    {
        float4 xv = *(const float4*)&x[nc*4];
        float r_[4];
        #pragma unroll
        for (int j = 0; j < 4; ++j) {
            int o = fg4 + j;
            float a = proj_b[o];
            a = fmaf(xv.x, proj_w[0*32 + o], a);
            a = fmaf(xv.y, proj_w[1*32 + o], a);
            a = fmaf(xv.z, proj_w[2*32 + o], a);
            a = fmaf(xv.w, proj_w[3*32 + o], a);
            r_[j] = fmaxf(a, 0.f);
        }
        if (valid) *(float4*)&h[n*32 + fg4] = make_float4(r_[0], r_[1], r_[2], r_[3]);
        *(float4*)&sm[xb + fg4] = make_float4(r_[0], r_[1], r_[2], r_[3]);
    }

    if (flag[0]) {
        float4* s4 = (float4*)sm;
        for (int i = tid; i < 768; i += 256) {
            const float4* src = (i < 256) ? (const float4*)MP
                              : (i < 512) ? (const float4*)MM
                                          : (const float4*)e2b;
            s4[i] = src[i & 255];
        }
        __syncthreads();
        #pragma unroll 1
        for (int cc = 0; cc < 3; ++cc) {
            float acc[4] = {0.f, 0.f, 0.f, 0.f};
            pass1_lds(sm, xb, cc*1024, fg4, acc);
            if (valid)
                *(float4*)&A[(size_t)n*96 + cc*32 + fg4] =
                    make_float4(acc[0], acc[1], acc[2], acc[3]);
        }
    } else {
        #pragma unroll 1
        for (int cg = 0; cg < 3; ++cg) {
            __syncthreads();
            float4* s4 = (float4*)sm;
            for (int i = tid; i < 768; i += 256) {
                int c = cg*3 + (i >> 8);
                const float4* src = (c < 8) ? (const float4*)(e2w + (size_t)c*1024)
                                            : (const float4*)e2b;
                s4[i] = src[i & 255];
            }
            __syncthreads();
            #pragma unroll 1
            for (int cc = 0; cc < 3; ++cc) {
                float acc[4] = {0.f, 0.f, 0.f, 0.f};
                pass1_lds(sm, xb, cc*1024, fg4, acc);
                if (valid)
                    *(float4*)&A[(size_t)n*288 + (cg*3+cc)*32 + fg4] =
                        make_float4(acc[0], acc[1], acc[2], acc[3]);
            }
        }
    }
}

// ---------------- fused iteration: CSR gather -> GRU -> h; next-table via LDS reuse; optional e=h·q ----------------
// LDS floats: ROOT[0,1024) WH[1024,4096) WI[4096,7168) X[7168,8320)
// After GRU: barrier, MW overwrites [0,3072), barrier, table GEMV.  32.5 KB -> 4 blocks/CU.
#define XGR 7168
__global__ __launch_bounds__(256, 4) void k_gru(
    float* __restrict__ h,
    const int* __restrict__ rowptr, const int* __restrict__ esrc, const float* __restrict__ eattr,
    const float* __restrict__ TIN, const int* __restrict__ flag,
    const float* __restrict__ root_w, const float* __restrict__ conv_b,
    const float* __restrict__ WI, const float* __restrict__ WH, const float* __restrict__ BS,
    const float* __restrict__ MP, const float* __restrict__ MM,
    const float* __restrict__ e2b, const float* __restrict__ e2w,
    const float* __restrict__ e1w, const float* __restrict__ e1b,
    const float* __restrict__ qvec, const int* __restrict__ batch,
    float* __restrict__ ebuf, unsigned int* __restrict__ segmax,
    float* __restrict__ TOUT, int N, int computeT, int computeE)
{
    __shared__ float sm[XGR + 1152];
    int tid = threadIdx.x;
    int fast = flag[0];
    {
        float4* s4 = (float4*)sm;
        const float4* r4  = (const float4*)root_w;
        const float4* wh4 = (const float4*)WH;
        const float4* wi4 = (const float4*)WI;
        for (int i = tid; i < 256; i += 256) s4[i] = r4[i];
        for (int i = tid; i < 768; i += 256) s4[256  + i] = wh4[i];
        for (int i = tid; i < 768; i += 256) s4[1024 + i] = wi4[i];
    }
    __syncthreads();

    int lane = tid & 63;
    int w = tid >> 6;
    int fg = lane & 7, fg4 = fg*4;
    int nw = lane >> 3;
    int n = (blockIdx.x * 4 + w) * 8 + nw;
    bool valid = (n < N);
    int nc = valid ? n : (N - 1);
    int xb = XGR + w*288 + nw*36;

    float4 hv4 = *(const float4*)&h[nc*32 + fg4];
    float hold[4] = {hv4.x, hv4.y, hv4.z, hv4.w};
    *(float4*)&sm[xb + fg4] = hv4;        // publish h row (wave-local)

    // ---- CSR gather: agg = sum over in-edges (latency hidden by 16 waves/CU) ----
    float av[4] = {0.f, 0.f, 0.f, 0.f};
    {
        int beg = rowptr[nc];
        int end = rowptr[nc + 1];
        if (fast) {
            for (int j = beg; j < end; ++j) {
                int src = esrc[j];
                float a = eattr[j];
                const float* base = TIN + (size_t)src * 96;
                float4 p = *(const float4*)&base[(a > 0.f ? 0 : 32) + fg4];
                float4 b = *(const float4*)&base[64 + fg4];
                av[0] += fmaf(a, p.x, b.x);
                av[1] += fmaf(a, p.y, b.y);
                av[2] += fmaf(a, p.z, b.z);
                av[3] += fmaf(a, p.w, b.w);
            }
        } else {
            for (int j = beg; j < end; ++j) {
                int src = esrc[j];
                float a = eattr[j];
                const float* Gp = TIN + (size_t)src * 288;
                float4 b = *(const float4*)&Gp[256 + fg4];
                float m0 = b.x, m1 = b.y, m2 = b.z, m3 = b.w;
                #pragma unroll
                for (int k = 0; k < 8; ++k) {
                    float t = fmaxf(fmaf(a, e1w[k], e1b[k]), 0.f);
                    float4 g = *(const float4*)&Gp[k*32 + fg4];
                    m0 = fmaf(t, g.x, m0); m1 = fmaf(t, g.y, m1);
                    m2 = fmaf(t, g.z, m2); m3 = fmaf(t, g.w, m3);
                }
                av[0] += m0; av[1] += m1; av[2] += m2; av[3] += m3;
            }
        }
    }

    // ---- out_pre = agg + conv_b + h@root_w ; gh2 = bh2 + h@WH2 ----
    float outv[4], gh2[4];
    {
        float4 cb4 = *(const float4*)&conv_b[fg4];
        outv[0]=av[0]+cb4.x; outv[1]=av[1]+cb4.y; outv[2]=av[2]+cb4.z; outv[3]=av[3]+cb4.w;
        float4 b3 = *(const float4*)&BS[96 + fg4];
        gh2[0]=b3.x; gh2[1]=b3.y; gh2[2]=b3.z; gh2[3]=b3.w;
    }
    pass2_lds(sm, xb, 0, 1024 + 2048, fg4, outv, gh2);

    float gh0[4] = {0.f,0.f,0.f,0.f};
    float gh1[4] = {0.f,0.f,0.f,0.f};
    pass2_lds(sm, xb, 1024, 2048, fg4, gh0, gh1);

    float outr[4];
    #pragma unroll
    for (int j = 0; j < 4; ++j) outr[j] = fmaxf(outv[j], 0.f);

    *(float4*)&sm[xb + fg4] = make_float4(outr[0], outr[1], outr[2], outr[3]);

    float gi0[4], gi1[4], gi2[4];
    {
        float4 b0 = *(const float4*)&BS[fg4];
        float4 b1 = *(const float4*)&BS[32 + fg4];
        float4 b2 = *(const float4*)&BS[64 + fg4];
        gi0[0]=b0.x; gi0[1]=b0.y; gi0[2]=b0.z; gi0[3]=b0.w;
        gi1[0]=b1.x; gi1[1]=b1.y; gi1[2]=b1.z; gi1[3]=b1.w;
        gi2[0]=b2.x; gi2[1]=b2.y; gi2[2]=b2.z; gi2[3]=b2.w;
    }
    pass2_lds(sm, xb, 4096, 5120, fg4, gi0, gi1);
    pass1_lds(sm, xb, 6144, fg4, gi2);

    float hnew[4];
    #pragma unroll
    for (int j = 0; j < 4; ++j) {
        float r = sigmoidf_(gi0[j] + gh0[j]);
        float z = sigmoidf_(gi1[j] + gh1[j]);
        float nn = tanhf(gi2[j] + r * gh2[j]);
        hnew[j] = (1.f - z) * nn + z * hold[j];
    }
    if (valid) *(float4*)&h[n*32 + fg4] = make_float4(hnew[0], hnew[1], hnew[2], hnew[3]);

    // ---- fused readout pass1: e = h_new · q, segment max ----
    if (computeE) {
        float4 qv = *(const float4*)&qvec[fg4];
        float e = hnew[0]*qv.x + hnew[1]*qv.y + hnew[2]*qv.z + hnew[3]*qv.w;
        e += __shfl_xor(e, 1, 64);
        e += __shfl_xor(e, 2, 64);
        e += __shfl_xor(e, 4, 64);
        if (valid && fg == 0) {
            ebuf[n] = e;
            atomicMax(&segmax[batch[n]], fenc(e));
        }
    }

    // ---- next-iteration table into TOUT; MW reuses ROOT/WH LDS (dead after GRU) ----
    if (computeT) {
        *(float4*)&sm[xb + fg4] = make_float4(hnew[0], hnew[1], hnew[2], hnew[3]);
        __syncthreads();                   // all waves done with ROOT/WH/WI reads
        float4* s4 = (float4*)sm;
        if (fast) {
            for (int i = tid; i < 768; i += 256) {
                const float4* src = (i < 256) ? (const float4*)MP
                                  : (i < 512) ? (const float4*)MM
                                              : (const float4*)e2b;
                s4[i] = src[i & 255];
            }
            __syncthreads();
            #pragma unroll 1
            for (int cc = 0; cc < 3; ++cc) {
                float acc[4] = {0.f, 0.f, 0.f, 0.f};
                pass1_lds(sm, xb, cc*1024, fg4, acc);
                if (valid)
                    *(float4*)&TOUT[(size_t)n*96 + cc*32 + fg4] =
                        make_float4(acc[0], acc[1], acc[2], acc[3]);
            }
        } else {
            #pragma unroll 1
            for (int cg = 0; cg < 3; ++cg) {
                __syncthreads();
                for (int i = tid; i < 768; i += 256) {
                    int c = cg*3 + (i >> 8);
                    const float4* src = (c < 8) ? (const float4*)(e2w + (size_t)c*1024)
                                                : (const float4*)e2b;
                    s4[i] = src[i & 255];
                }
                __syncthreads();
                #pragma unroll 1
                for (int cc = 0; cc < 3; ++cc) {
                    float acc[4] = {0.f, 0.f, 0.f, 0.f};
                    pass1_lds(sm, xb, cc*1024, fg4, acc);
                    if (valid)
                        *(float4*)&TOUT[(size_t)n*288 + (cg*3+cc)*32 + fg4] =
                            make_float4(acc[0], acc[1], acc[2], acc[3]);
                }
            }
        }
    }
}

// ---------------- readout pass2: a = exp(e - emax); vsum += a*h; ssum += a ----------------
__global__ __launch_bounds__(256) void k_pass2(
    const float* __restrict__ h, const int* __restrict__ batch,
    const float* __restrict__ ebuf, const unsigned int* __restrict__ segmax,
    float* __restrict__ ssum, float* __restrict__ vsum, int N)
{
    int b = blockIdx.x / CHUNKS;
    int c = blockIdx.x % CHUNKS;
    int lo = 0, hi = N;
    while (lo < hi) { int mid = (lo + hi) >> 1; if (batch[mid] < b) lo = mid + 1; else hi = mid; }
    int s = lo;
    lo = 0; hi = N;
    while (lo < hi) { int mid = (lo + hi) >> 1; if (batch[mid] < b + 1) lo = mid + 1; else hi = mid; }
    int e = lo;
    int len = e - s;
    int per = (len + CHUNKS - 1) / CHUNKS;
    int n0 = s + c * per;
    int n1 = min(n0 + per, e);

    int tid = threadIdx.x;
    int ln = tid >> 5, o = tid & 31;
    float emax = fdec(segmax[b]);
    float vacc = 0.f, sacc = 0.f;
    for (int nn = n0 + ln; nn < n1; nn += 8) {
        float a = expf(ebuf[nn] - emax);
        vacc += a * h[nn * H + o];
        if (o == 0) sacc += a;
    }
    __shared__ float vsh[8][H];
    __shared__ float ssh[8];
    vsh[ln][o] = vacc;
    if (o == 0) ssh[ln] = sacc;
    __syncthreads();
    if (tid < H) {
        float v = 0.f;
        #pragma unroll
        for (int g = 0; g < 8; ++g) v += vsh[g][tid];
        atomicAdd(&vsum[b * H + tid], v);
    } else if (tid == H) {
        float stot = 0.f;
        #pragma unroll
        for (int g = 0; g < 8; ++g) stot += ssh[g];
        atomicAdd(&ssum[b], stot);
    }
}

// ---------------- final MLP on (16, 64) ----------------
__global__ __launch_bounds__(512) void k_mlp(
    const float* __restrict__ qvec, const float* __restrict__ ssum, const float* __restrict__ vsum,
    const float* __restrict__ f1w, const float* __restrict__ f1b,
    const float* __restrict__ f2w, const float* __restrict__ f2b,
    const float* __restrict__ f3w, const float* __restrict__ f3b,
    float* __restrict__ out)
{
    __shared__ float qsm[BSEG][2 * H];
    __shared__ float o1[BSEG][H];
    __shared__ float o2[BSEG][H];
    int tid = threadIdx.x;
    int b = tid >> 5, j = tid & 31;
    float st = ssum[b];
    qsm[b][j] = qvec[j];
    qsm[b][H + j] = (st > 0.f) ? vsum[b * H + j] / st : 0.f;
    __syncthreads();
    float acc = f1b[j];
    for (int i = 0; i < 2 * H; ++i) acc += qsm[b][i] * f1w[i * H + j];
    o1[b][j] = fmaxf(acc, 0.f);
    __syncthreads();
    acc = f2b[j];
    for (int i = 0; i < H; ++i) acc += o1[b][i] * f2w[i * H + j];
    o2[b][j] = fmaxf(acc, 0.f);
    __syncthreads();
    float v = o2[b][j] * f3w[j];
    #pragma unroll
    for (int m = 16; m >= 1; m >>= 1) v += __shfl_xor(v, m);
    if (j == 0) out[b] = v + f3b[0];
}

extern "C" void kernel_launch(void* const* d_in, const int* in_sizes, int n_in,
                              void* d_out, int out_size, void* d_ws, size_t ws_size,
                              hipStream_t stream)
{
    const float* x      = (const float*)d_in[0];
    const int*   ei     = (const int*)d_in[1];
    const float* ea     = (const float*)d_in[2];
    const int*   batch  = (const int*)d_in[3];
    const float* proj_w = (const float*)d_in[4];
    const float* proj_b = (const float*)d_in[5];
    const float* e1w    = (const float*)d_in[6];
    const float* e1b    = (const float*)d_in[7];
    const float* e2w    = (const float*)d_in[8];
    const float* e2b    = (const float*)d_in[9];
    const float* root_w = (const float*)d_in[10];
    const float* conv_b = (const float*)d_in[11];
    const float* gru_wi = (const float*)d_in[12];
    const float* gru_wh = (const float*)d_in[13];
    const float* gru_bi = (const float*)d_in[14];
    const float* gru_bh = (const float*)d_in[15];
    const float* lstm_bi = (const float*)d_in[18];
    const float* lstm_bh = (const float*)d_in[19];
    const float* f1w    = (const float*)d_in[20];
    const float* f1b    = (const float*)d_in[21];
    const float* f2w    = (const float*)d_in[22];
    const float* f2b    = (const float*)d_in[23];
    const float* f3w    = (const float*)d_in[24];
    const float* f3b    = (const float*)d_in[25];

    const int N = in_sizes[0] / 4;
    const int E = in_sizes[2];

    float* ws   = (float*)d_ws;
    float* h    = ws;                        // N*32
    float* A    = h + (size_t)N * H;         // N*288 (ping)
    float* Bb   = A + (size_t)N * 288;       // N*288 (pong)
    float* ebuf = Bb + (size_t)N * 288;      // N
    float* qvec = ebuf + N;                  // 32
    unsigned int* segmax = (unsigned int*)(qvec + H);  // 16
    float* ssum = (float*)(segmax + BSEG);   // 16
    float* vsum = ssum + BSEG;               // 512
    float* WI   = vsum + BSEG * H;           // 3072
    float* WH   = WI + 3072;                 // 3072
    float* BS   = WH + 3072;                 // 128
    float* MP   = BS + 128;                  // 1024
    float* MM   = MP + 1024;                 // 1024
    int*   flag = (int*)(MM + 1024);         // 1
    int*   cnt    = flag + 1;                // N
    int*   rowptr = cnt + N;                 // N+1
    int*   cursor = rowptr + N + 1;          // N
    int*   esrc   = cursor + N;              // E
    float* eattr  = (float*)(esrc + E);      // E

    const int nwaves = (N + 7) / 8;          // 8 nodes per wave
    const int nb4 = (nwaves + 3) / 4;        // 4 waves per block
    const int cblocks = (E + 255) / 256;

    k_prep<<<1, 512, 0, stream>>>(gru_wi, gru_wh, gru_bi, gru_bh, lstm_bi, lstm_bh,
                                  e1w, e1b, e2w,
                                  WI, WH, BS, MP, MM, flag, qvec, segmax, ssum, vsum, cnt, N);
    k_count<<<cblocks, 256, 0, stream>>>(ei, cnt, E);
    k_scan<<<1, 1024, 0, stream>>>(cnt, rowptr, cursor, N);
    k_scatter<<<cblocks, 256, 0, stream>>>(ei, ea, cursor, esrc, eattr, E);
    k_tab<<<nb4, 256, 0, stream>>>(x, proj_w, proj_b, e2w, e2b, MP, MM, flag, h, A, N);

    k_gru<<<nb4, 256, 0, stream>>>(h, rowptr, esrc, eattr, A, flag, root_w, conv_b,
                                   WI, WH, BS, MP, MM, e2b, e2w, e1w, e1b,
                                   qvec, batch, ebuf, segmax, Bb, N, 1, 0);
    k_gru<<<nb4, 256, 0, stream>>>(h, rowptr, esrc, eattr, Bb, flag, root_w, conv_b,
                                   WI, WH, BS, MP, MM, e2b, e2w, e1w, e1b,
                                   qvec, batch, ebuf, segmax, A, N, 1, 0);
    k_gru<<<nb4, 256, 0, stream>>>(h, rowptr, esrc, eattr, A, flag, root_w, conv_b,
                                   WI, WH, BS, MP, MM, e2b, e2w, e1w, e1b,
                                   qvec, batch, ebuf, segmax, Bb, N, 0, 1);

    k_pass2<<<BSEG * CHUNKS, 256, 0, stream>>>(h, batch, ebuf, segmax, ssum, vsum, N);
    k_mlp<<<1, 512, 0, stream>>>(qvec, ssum, vsum, f1w, f1b, f2w, f2b, f3w, f3b, (float*)d_out);
}

// Round 12
// 182.575 us; speedup vs baseline: 2.2197x; 2.1727x over previous
//
#include <hip/hip_runtime.h>
#include <math.h>

#define H 32
#define BSEG 16
#define CHUNKS 32

__device__ __forceinline__ float sigmoidf_(float x){ return 1.f/(1.f+expf(-x)); }

__device__ __forceinline__ unsigned int fenc(float f) {
    int i = __float_as_int(f);
    return (i >= 0) ? ((unsigned int)i | 0x80000000u) : ~(unsigned int)i;
}
__device__ __forceinline__ float fdec(unsigned int u) {
    int i = (u & 0x80000000u) ? (int)(u & 0x7FFFFFFFu) : (int)(~u);
    return __int_as_float(i);
}

// ---------------- prep: transposed GRU weights, fused biases, qvec, masked edge matrices, zero cnt ----------------
__global__ __launch_bounds__(512) void k_prep(
    const float* __restrict__ gru_wi, const float* __restrict__ gru_wh,
    const float* __restrict__ gru_bi, const float* __restrict__ gru_bh,
    const float* __restrict__ lstm_bi, const float* __restrict__ lstm_bh,
    const float* __restrict__ e1w, const float* __restrict__ e1b, const float* __restrict__ e2w,
    float* __restrict__ WI, float* __restrict__ WH, float* __restrict__ BS,
    float* __restrict__ MP, float* __restrict__ MM, int* __restrict__ flag,
    float* __restrict__ qvec, unsigned int* __restrict__ segmax,
    float* __restrict__ ssum, float* __restrict__ vsum,
    int* __restrict__ cnt, int N)
{
    int t = threadIdx.x;
    for (int i = t; i < N; i += 512) cnt[i] = 0;
    for (int idx = t; idx < 3072; idx += 512) {
        int k = idx >> 10, rem = idx & 1023, i = rem >> 5, o = rem & 31;
        WI[idx] = gru_wi[(k*32 + o)*32 + i];
        WH[idx] = gru_wh[(k*32 + o)*32 + i];
    }
    for (int idx = t; idx < 1024; idx += 512) {
        float mp = 0.f, mm = 0.f;
        #pragma unroll
        for (int k = 0; k < 8; ++k) {
            float w = e1w[k];
            float v = e2w[k*1024 + idx];
            if (w > 0.f) mp = fmaf(w, v, mp);
            if (w < 0.f) mm = fmaf(w, v, mm);
        }
        MP[idx] = mp;
        MM[idx] = mm;
    }
    if (t == 0) {
        int z = 1;
        for (int k = 0; k < 8; ++k) if (e1b[k] != 0.f) z = 0;
        flag[0] = z;
    }
    if (t < 32) {
        BS[t]      = gru_bi[t]      + gru_bh[t];
        BS[32 + t] = gru_bi[32 + t] + gru_bh[32 + t];
        BS[64 + t] = gru_bi[64 + t];
        BS[96 + t] = gru_bh[64 + t];
    }
    if (t < H) {
        float g0 = lstm_bi[t] + lstm_bh[t];
        float g2 = lstm_bi[2*H + t] + lstm_bh[2*H + t];
        float g3 = lstm_bi[3*H + t] + lstm_bh[3*H + t];
        float ig = sigmoidf_(g0);
        float gg = tanhf(g2);
        float og = sigmoidf_(g3);
        qvec[t] = og * tanhf(ig * gg);
    }
    for (int i = t; i < BSEG; i += 512) { segmax[i] = 0u; ssum[i] = 0.f; }
    for (int i = t; i < BSEG*H; i += 512) vsum[i] = 0.f;
}

// ---------------- CSR build: count -> scan -> scatter ----------------
__global__ __launch_bounds__(256) void k_count(const int* __restrict__ ei, int* __restrict__ cnt, int E)
{
    int e = blockIdx.x * 256 + threadIdx.x;
    if (e < E) atomicAdd(&cnt[ei[E + e]], 1);
}

__global__ __launch_bounds__(1024) void k_scan(
    const int* __restrict__ cnt, int* __restrict__ rowptr, int* __restrict__ cursor, int N)
{
    __shared__ int part[1024];
    int t = threadIdx.x;
    int chunk = (N + 1023) >> 10;
    int base = t * chunk;
    int s = 0;
    for (int i = 0; i < chunk; ++i) {
        int idx = base + i;
        if (idx < N) s += cnt[idx];
    }
    part[t] = s;
    __syncthreads();
    for (int off = 1; off < 1024; off <<= 1) {
        int add = (t >= off) ? part[t - off] : 0;
        __syncthreads();
        part[t] += add;
        __syncthreads();
    }
    int run = part[t] - s;                 // exclusive prefix for this chunk
    for (int i = 0; i < chunk; ++i) {
        int idx = base + i;
        if (idx < N) {
            rowptr[idx] = run;
            cursor[idx] = run;
            run += cnt[idx];
        }
    }
    if (t == 1023) rowptr[N] = part[1023];
}

__global__ __launch_bounds__(256) void k_scatter(
    const int* __restrict__ ei, const float* __restrict__ ea, int* __restrict__ cursor,
    int* __restrict__ esrc, float* __restrict__ eattr, int E)
{
    int e = blockIdx.x * 256 + threadIdx.x;
    if (e >= E) return;
    int dst = ei[E + e];
    int pos = atomicAdd(&cursor[dst], 1);
    esrc[pos] = ei[e];
    eattr[pos] = ea[e];
}

// ---- LDS-based K=32 passes (x row broadcast across node's 8 fg-lanes; weights across 8 node-lanes) ----
__device__ __forceinline__ void pass2_lds(const float* sm, int xb, int w0, int w1, int fg4,
                                          float a[4], float b[4])
{
    #pragma unroll 2
    for (int i4 = 0; i4 < 32; i4 += 4) {
        float4 xv  = *(const float4*)&sm[xb + i4];
        float4 w00 = *(const float4*)&sm[w0 + (i4+0)*32 + fg4];
        float4 w01 = *(const float4*)&sm[w0 + (i4+1)*32 + fg4];
        float4 w02 = *(const float4*)&sm[w0 + (i4+2)*32 + fg4];
        float4 w03 = *(const float4*)&sm[w0 + (i4+3)*32 + fg4];
        float4 w10 = *(const float4*)&sm[w1 + (i4+0)*32 + fg4];
        float4 w11 = *(const float4*)&sm[w1 + (i4+1)*32 + fg4];
        float4 w12 = *(const float4*)&sm[w1 + (i4+2)*32 + fg4];
        float4 w13 = *(const float4*)&sm[w1 + (i4+3)*32 + fg4];
        a[0]=fmaf(xv.x,w00.x,a[0]); a[1]=fmaf(xv.x,w00.y,a[1]); a[2]=fmaf(xv.x,w00.z,a[2]); a[3]=fmaf(xv.x,w00.w,a[3]);
        a[0]=fmaf(xv.y,w01.x,a[0]); a[1]=fmaf(xv.y,w01.y,a[1]); a[2]=fmaf(xv.y,w01.z,a[2]); a[3]=fmaf(xv.y,w01.w,a[3]);
        a[0]=fmaf(xv.z,w02.x,a[0]); a[1]=fmaf(xv.z,w02.y,a[1]); a[2]=fmaf(xv.z,w02.z,a[2]); a[3]=fmaf(xv.z,w02.w,a[3]);
        a[0]=fmaf(xv.w,w03.x,a[0]); a[1]=fmaf(xv.w,w03.y,a[1]); a[2]=fmaf(xv.w,w03.z,a[2]); a[3]=fmaf(xv.w,w03.w,a[3]);
        b[0]=fmaf(xv.x,w10.x,b[0]); b[1]=fmaf(xv.x,w10.y,b[1]); b[2]=fmaf(xv.x,w10.z,b[2]); b[3]=fmaf(xv.x,w10.w,b[3]);
        b[0]=fmaf(xv.y,w11.x,b[0]); b[1]=fmaf(xv.y,w11.y,b[1]); b[2]=fmaf(xv.y,w11.z,b[2]); b[3]=fmaf(xv.y,w11.w,b[3]);
        b[0]=fmaf(xv.z,w12.x,b[0]); b[1]=fmaf(xv.z,w12.y,b[1]); b[2]=fmaf(xv.z,w12.z,b[2]); b[3]=fmaf(xv.z,w12.w,b[3]);
        b[0]=fmaf(xv.w,w13.x,b[0]); b[1]=fmaf(xv.w,w13.y,b[1]); b[2]=fmaf(xv.w,w13.z,b[2]); b[3]=fmaf(xv.w,w13.w,b[3]);
    }
}

__device__ __forceinline__ void pass1_lds(const float* sm, int xb, int w0, int fg4, float a[4])
{
    #pragma unroll 2
    for (int i4 = 0; i4 < 32; i4 += 4) {
        float4 xv  = *(const float4*)&sm[xb + i4];
        float4 w00 = *(const float4*)&sm[w0 + (i4+0)*32 + fg4];
        float4 w01 = *(const float4*)&sm[w0 + (i4+1)*32 + fg4];
        float4 w02 = *(const float4*)&sm[w0 + (i4+2)*32 + fg4];
        float4 w03 = *(const float4*)&sm[w0 + (i4+3)*32 + fg4];
        a[0]=fmaf(xv.x,w00.x,a[0]); a[1]=fmaf(xv.x,w00.y,a[1]); a[2]=fmaf(xv.x,w00.z,a[2]); a[3]=fmaf(xv.x,w00.w,a[3]);
        a[0]=fmaf(xv.y,w01.x,a[0]); a[1]=fmaf(xv.y,w01.y,a[1]); a[2]=fmaf(xv.y,w01.z,a[2]); a[3]=fmaf(xv.y,w01.w,a[3]);
        a[0]=fmaf(xv.z,w02.x,a[0]); a[1]=fmaf(xv.z,w02.y,a[1]); a[2]=fmaf(xv.z,w02.z,a[2]); a[3]=fmaf(xv.z,w02.w,a[3]);
        a[0]=fmaf(xv.w,w03.x,a[0]); a[1]=fmaf(xv.w,w03.y,a[1]); a[2]=fmaf(xv.w,w03.z,a[2]); a[3]=fmaf(xv.w,w03.w,a[3]);
    }
}

// ---------------- tab: proj fused + initial table. fast: T[n] stride 96; fallback: G[n] stride 288 ----------------
#define TW 3072
__global__ __launch_bounds__(256, 2) void k_tab(
    const float* __restrict__ x, const float* __restrict__ proj_w, const float* __restrict__ proj_b,
    const float* __restrict__ e2w, const float* __restrict__ e2b,
    const float* __restrict__ MP, const float* __restrict__ MM, const int* __restrict__ flag,
    float* __restrict__ h, float* __restrict__ A, int N)
{
    __shared__ float sm[TW + 4*288];
    int tid = threadIdx.x;
    int lane = tid & 63;
    int w = tid >> 6;
    int fg = lane & 7, fg4 = fg*4;
    int nw = lane >> 3;
    int n = (blockIdx.x * 4 + w) * 8 + nw;
    bool valid = (n < N);
    int nc = valid ? n : (N - 1);
    int xb = TW + w*288 + nw*36;

    // proj fused: h row for this node
    {
        float4 xv = *(const float4*)&x[nc*4];
        float r_[4];
        #pragma unroll
        for (int j = 0; j < 4; ++j) {
            int o = fg4 + j;
            float a = proj_b[o];
            a = fmaf(xv.x, proj_w[0*32 + o], a);
            a = fmaf(xv.y, proj_w[1*32 + o], a);
            a = fmaf(xv.z, proj_w[2*32 + o], a);
            a = fmaf(xv.w, proj_w[3*32 + o], a);
            r_[j] = fmaxf(a, 0.f);
        }
        if (valid) *(float4*)&h[n*32 + fg4] = make_float4(r_[0], r_[1], r_[2], r_[3]);
        *(float4*)&sm[xb + fg4] = make_float4(r_[0], r_[1], r_[2], r_[3]);
    }

    if (flag[0]) {
        float4* s4 = (float4*)sm;
        for (int i = tid; i < 768; i += 256) {
            const float4* src = (i < 256) ? (const float4*)MP
                              : (i < 512) ? (const float4*)MM
                                          : (const float4*)e2b;
            s4[i] = src[i & 255];
        }
        __syncthreads();
        #pragma unroll 1
        for (int cc = 0; cc < 3; ++cc) {
            float acc[4] = {0.f, 0.f, 0.f, 0.f};
            pass1_lds(sm, xb, cc*1024, fg4, acc);
            if (valid)
                *(float4*)&A[(size_t)n*96 + cc*32 + fg4] =
                    make_float4(acc[0], acc[1], acc[2], acc[3]);
        }
    } else {
        #pragma unroll 1
        for (int cg = 0; cg < 3; ++cg) {
            __syncthreads();
            float4* s4 = (float4*)sm;
            for (int i = tid; i < 768; i += 256) {
                int c = cg*3 + (i >> 8);
                const float4* src = (c < 8) ? (const float4*)(e2w + (size_t)c*1024)
                                            : (const float4*)e2b;
                s4[i] = src[i & 255];
            }
            __syncthreads();
            #pragma unroll 1
            for (int cc = 0; cc < 3; ++cc) {
                float acc[4] = {0.f, 0.f, 0.f, 0.f};
                pass1_lds(sm, xb, cc*1024, fg4, acc);
                if (valid)
                    *(float4*)&A[(size_t)n*288 + (cg*3+cc)*32 + fg4] =
                        make_float4(acc[0], acc[1], acc[2], acc[3]);
            }
        }
    }
}

// ---------------- fused iteration (R9 structure): CSR gather (2-way MLP) -> GRU -> h; next-table ----------------
// LDS floats: ROOT[0,1024) WH[1024,4096) WI[4096,7168) MW[7168,10240) X[10240,+1152)
#define XGR 10240
__global__ __launch_bounds__(256, 2) void k_gru(
    float* __restrict__ h,
    const int* __restrict__ rowptr, const int* __restrict__ esrc, const float* __restrict__ eattr,
    const float* __restrict__ TIN, const int* __restrict__ flag,
    const float* __restrict__ root_w, const float* __restrict__ conv_b,
    const float* __restrict__ WI, const float* __restrict__ WH, const float* __restrict__ BS,
    const float* __restrict__ MP, const float* __restrict__ MM,
    const float* __restrict__ e2b, const float* __restrict__ e2w,
    const float* __restrict__ e1w, const float* __restrict__ e1b,
    float* __restrict__ TOUT, int N, int computeT)
{
    __shared__ float sm[XGR + 1152];
    int tid = threadIdx.x;
    int fast = flag[0];
    {
        float4* s4 = (float4*)sm;
        const float4* r4  = (const float4*)root_w;
        const float4* wh4 = (const float4*)WH;
        const float4* wi4 = (const float4*)WI;
        for (int i = tid; i < 256; i += 256) s4[i] = r4[i];
        for (int i = tid; i < 768; i += 256) s4[256  + i] = wh4[i];
        for (int i = tid; i < 768; i += 256) s4[1024 + i] = wi4[i];
        if (computeT && fast) {
            for (int i = tid; i < 768; i += 256) {
                const float4* src = (i < 256) ? (const float4*)MP
                                  : (i < 512) ? (const float4*)MM
                                              : (const float4*)e2b;
                s4[1792 + i] = src[i & 255];
            }
        }
    }
    __syncthreads();

    int lane = tid & 63;
    int w = tid >> 6;
    int fg = lane & 7, fg4 = fg*4;
    int nw = lane >> 3;
    int n = (blockIdx.x * 4 + w) * 8 + nw;
    bool valid = (n < N);
    int nc = valid ? n : (N - 1);
    int xb = XGR + w*288 + nw*36;

    float4 hv4 = *(const float4*)&h[nc*32 + fg4];
    float hold[4] = {hv4.x, hv4.y, hv4.z, hv4.w};
    *(float4*)&sm[xb + fg4] = hv4;        // publish h row (wave-local)

    // ---- CSR gather: agg = sum over in-edges; 2-way unroll for memory-level parallelism ----
    float av[4] = {0.f, 0.f, 0.f, 0.f};
    {
        int beg = rowptr[nc];
        int end = rowptr[nc + 1];
        if (fast) {
            int j = beg;
            for (; j + 1 < end; j += 2) {
                int s0 = esrc[j];
                int s1 = esrc[j + 1];
                float a0 = eattr[j];
                float a1 = eattr[j + 1];
                const float* b0p = TIN + (size_t)s0 * 96;
                const float* b1p = TIN + (size_t)s1 * 96;
                float4 p0 = *(const float4*)&b0p[(a0 > 0.f ? 0 : 32) + fg4];
                float4 q0 = *(const float4*)&b0p[64 + fg4];
                float4 p1 = *(const float4*)&b1p[(a1 > 0.f ? 0 : 32) + fg4];
                float4 q1 = *(const float4*)&b1p[64 + fg4];
                av[0] += fmaf(a0, p0.x, q0.x) + fmaf(a1, p1.x, q1.x);
                av[1] += fmaf(a0, p0.y, q0.y) + fmaf(a1, p1.y, q1.y);
                av[2] += fmaf(a0, p0.z, q0.z) + fmaf(a1, p1.z, q1.z);
                av[3] += fmaf(a0, p0.w, q0.w) + fmaf(a1, p1.w, q1.w);
            }
            if (j < end) {
                int s0 = esrc[j];
                float a0 = eattr[j];
                const float* b0p = TIN + (size_t)s0 * 96;
                float4 p0 = *(const float4*)&b0p[(a0 > 0.f ? 0 : 32) + fg4];
                float4 q0 = *(const float4*)&b0p[64 + fg4];
                av[0] += fmaf(a0, p0.x, q0.x);
                av[1] += fmaf(a0, p0.y, q0.y);
                av[2] += fmaf(a0, p0.z, q0.z);
                av[3] += fmaf(a0, p0.w, q0.w);
            }
        } else {
            for (int j = beg; j < end; ++j) {
                int src = esrc[j];
                float a = eattr[j];
                const float* Gp = TIN + (size_t)src * 288;
                float4 b = *(const float4*)&Gp[256 + fg4];
                float m0 = b.x, m1 = b.y, m2 = b.z, m3 = b.w;
                #pragma unroll
                for (int k = 0; k < 8; ++k) {
                    float t = fmaxf(fmaf(a, e1w[k], e1b[k]), 0.f);
                    float4 g = *(const float4*)&Gp[k*32 + fg4];
                    m0 = fmaf(t, g.x, m0); m1 = fmaf(t, g.y, m1);
                    m2 = fmaf(t, g.z, m2); m3 = fmaf(t, g.w, m3);
                }
                av[0] += m0; av[1] += m1; av[2] += m2; av[3] += m3;
            }
        }
    }

    // ---- out_pre = agg + conv_b + h@root_w ; gh2 = bh2 + h@WH2 ----
    float outv[4], gh2[4];
    {
        float4 cb4 = *(const float4*)&conv_b[fg4];
        outv[0]=av[0]+cb4.x; outv[1]=av[1]+cb4.y; outv[2]=av[2]+cb4.z; outv[3]=av[3]+cb4.w;
        float4 b3 = *(const float4*)&BS[96 + fg4];
        gh2[0]=b3.x; gh2[1]=b3.y; gh2[2]=b3.z; gh2[3]=b3.w;
    }
    pass2_lds(sm, xb, 0, 1024 + 2048, fg4, outv, gh2);

    float gh0[4] = {0.f,0.f,0.f,0.f};
    float gh1[4] = {0.f,0.f,0.f,0.f};
    pass2_lds(sm, xb, 1024, 2048, fg4, gh0, gh1);

    float outr[4];
    #pragma unroll
    for (int j = 0; j < 4; ++j) outr[j] = fmaxf(outv[j], 0.f);

    *(float4*)&sm[xb + fg4] = make_float4(outr[0], outr[1], outr[2], outr[3]);

    float gi0[4], gi1[4], gi2[4];
    {
        float4 b0 = *(const float4*)&BS[fg4];
        float4 b1 = *(const float4*)&BS[32 + fg4];
        float4 b2 = *(const float4*)&BS[64 + fg4];
        gi0[0]=b0.x; gi0[1]=b0.y; gi0[2]=b0.z; gi0[3]=b0.w;
        gi1[0]=b1.x; gi1[1]=b1.y; gi1[2]=b1.z; gi1[3]=b1.w;
        gi2[0]=b2.x; gi2[1]=b2.y; gi2[2]=b2.z; gi2[3]=b2.w;
    }
    pass2_lds(sm, xb, 4096, 5120, fg4, gi0, gi1);
    pass1_lds(sm, xb, 6144, fg4, gi2);

    float hnew[4];
    #pragma unroll
    for (int j = 0; j < 4; ++j) {
        float r = sigmoidf_(gi0[j] + gh0[j]);
        float z = sigmoidf_(gi1[j] + gh1[j]);
        float nn = tanhf(gi2[j] + r * gh2[j]);
        hnew[j] = (1.f - z) * nn + z * hold[j];
    }
    if (valid) *(float4*)&h[n*32 + fg4] = make_float4(hnew[0], hnew[1], hnew[2], hnew[3]);

    // ---- next-iteration table into TOUT (MW pre-staged at kernel top; no extra barriers) ----
    if (computeT) {
        *(float4*)&sm[xb + fg4] = make_float4(hnew[0], hnew[1], hnew[2], hnew[3]);
        if (fast) {
            #pragma unroll 1
            for (int cc = 0; cc < 3; ++cc) {
                float acc[4] = {0.f, 0.f, 0.f, 0.f};
                pass1_lds(sm, xb, 7168 + cc*1024, fg4, acc);
                if (valid)
                    *(float4*)&TOUT[(size_t)n*96 + cc*32 + fg4] =
                        make_float4(acc[0], acc[1], acc[2], acc[3]);
            }
        } else {
            #pragma unroll 1
            for (int cg = 0; cg < 3; ++cg) {
                __syncthreads();
                float4* s4 = (float4*)sm;
                for (int i = tid; i < 768; i += 256) {
                    int c = cg*3 + (i >> 8);
                    const float4* src = (c < 8) ? (const float4*)(e2w + (size_t)c*1024)
                                                : (const float4*)e2b;
                    s4[1792 + i] = src[i & 255];
                }
                __syncthreads();
                #pragma unroll 1
                for (int cc = 0; cc < 3; ++cc) {
                    float acc[4] = {0.f, 0.f, 0.f, 0.f};
                    pass1_lds(sm, xb, 7168 + cc*1024, fg4, acc);
                    if (valid)
                        *(float4*)&TOUT[(size_t)n*288 + (cg*3+cc)*32 + fg4] =
                            make_float4(acc[0], acc[1], acc[2], acc[3]);
                }
            }
        }
    }
}

// ---------------- readout pass1: e[n] = h[n]·q, segment max ----------------
__global__ __launch_bounds__(256) void k_pass1(
    const float* __restrict__ h, const int* __restrict__ batch,
    const float* __restrict__ qvec, float* __restrict__ ebuf,
    unsigned int* __restrict__ segmax, int N)
{
    int b = blockIdx.x / CHUNKS;
    int c = blockIdx.x % CHUNKS;
    int lo = 0, hi = N;
    while (lo < hi) { int mid = (lo + hi) >> 1; if (batch[mid] < b) lo = mid + 1; else hi = mid; }
    int s = lo;
    lo = 0; hi = N;
    while (lo < hi) { int mid = (lo + hi) >> 1; if (batch[mid] < b + 1) lo = mid + 1; else hi = mid; }
    int e = lo;
    int len = e - s;
    int per = (len + CHUNKS - 1) / CHUNKS;
    int n0 = s + c * per;
    int n1 = min(n0 + per, e);

    int tid = threadIdx.x;
    int ln = tid >> 5, o = tid & 31;
    float qv = qvec[o];
    float mloc = -INFINITY;
    for (int nn = n0 + ln; nn < n1; nn += 8) {
        float v = h[nn * H + o] * qv;
        #pragma unroll
        for (int m = 16; m >= 1; m >>= 1) v += __shfl_xor(v, m);
        if (o == 0) ebuf[nn] = v;
        mloc = fmaxf(mloc, v);
    }
    __shared__ float red[256];
    red[tid] = mloc;
    __syncthreads();
    for (int st = 128; st >= 1; st >>= 1) {
        if (tid < st) red[tid] = fmaxf(red[tid], red[tid + st]);
        __syncthreads();
    }
    if (tid == 0 && n0 < n1) atomicMax(&segmax[b], fenc(red[0]));
}

// ---------------- readout pass2: a = exp(e - emax); vsum += a*h; ssum += a ----------------
__global__ __launch_bounds__(256) void k_pass2(
    const float* __restrict__ h, const int* __restrict__ batch,
    const float* __restrict__ ebuf, const unsigned int* __restrict__ segmax,
    float* __restrict__ ssum, float* __restrict__ vsum, int N)
{
    int b = blockIdx.x / CHUNKS;
    int c = blockIdx.x % CHUNKS;
    int lo = 0, hi = N;
    while (lo < hi) { int mid = (lo + hi) >> 1; if (batch[mid] < b) lo = mid + 1; else hi = mid; }
    int s = lo;
    lo = 0; hi = N;
    while (lo < hi) { int mid = (lo + hi) >> 1; if (batch[mid] < b + 1) lo = mid + 1; else hi = mid; }
    int e = lo;
    int len = e - s;
    int per = (len + CHUNKS - 1) / CHUNKS;
    int n0 = s + c * per;
    int n1 = min(n0 + per, e);

    int tid = threadIdx.x;
    int ln = tid >> 5, o = tid & 31;
    float emax = fdec(segmax[b]);
    float vacc = 0.f, sacc = 0.f;
    for (int nn = n0 + ln; nn < n1; nn += 8) {
        float a = expf(ebuf[nn] - emax);
        vacc += a * h[nn * H + o];
        if (o == 0) sacc += a;
    }
    __shared__ float vsh[8][H];
    __shared__ float ssh[8];
    vsh[ln][o] = vacc;
    if (o == 0) ssh[ln] = sacc;
    __syncthreads();
    if (tid < H) {
        float v = 0.f;
        #pragma unroll
        for (int g = 0; g < 8; ++g) v += vsh[g][tid];
        atomicAdd(&vsum[b * H + tid], v);
    } else if (tid == H) {
        float stot = 0.f;
        #pragma unroll
        for (int g = 0; g < 8; ++g) stot += ssh[g];
        atomicAdd(&ssum[b], stot);
    }
}

// ---------------- final MLP on (16, 64) ----------------
__global__ __launch_bounds__(512) void k_mlp(
    const float* __restrict__ qvec, const float* __restrict__ ssum, const float* __restrict__ vsum,
    const float* __restrict__ f1w, const float* __restrict__ f1b,
    const float* __restrict__ f2w, const float* __restrict__ f2b,
    const float* __restrict__ f3w, const float* __restrict__ f3b,
    float* __restrict__ out)
{
    __shared__ float qsm[BSEG][2 * H];
    __shared__ float o1[BSEG][H];
    __shared__ float o2[BSEG][H];
    int tid = threadIdx.x;
    int b = tid >> 5, j = tid & 31;
    float st = ssum[b];
    qsm[b][j] = qvec[j];
    qsm[b][H + j] = (st > 0.f) ? vsum[b * H + j] / st : 0.f;
    __syncthreads();
    float acc = f1b[j];
    for (int i = 0; i < 2 * H; ++i) acc += qsm[b][i] * f1w[i * H + j];
    o1[b][j] = fmaxf(acc, 0.f);
    __syncthreads();
    acc = f2b[j];
    for (int i = 0; i < H; ++i) acc += o1[b][i] * f2w[i * H + j];
    o2[b][j] = fmaxf(acc, 0.f);
    __syncthreads();
    float v = o2[b][j] * f3w[j];
    #pragma unroll
    for (int m = 16; m >= 1; m >>= 1) v += __shfl_xor(v, m);
    if (j == 0) out[b] = v + f3b[0];
}

extern "C" void kernel_launch(void* const* d_in, const int* in_sizes, int n_in,
                              void* d_out, int out_size, void* d_ws, size_t ws_size,
                              hipStream_t stream)
{
    const float* x      = (const float*)d_in[0];
    const int*   ei     = (const int*)d_in[1];
    const float* ea     = (const float*)d_in[2];
    const int*   batch  = (const int*)d_in[3];
    const float* proj_w = (const float*)d_in[4];
    const float* proj_b = (const float*)d_in[5];
    const float* e1w    = (const float*)d_in[6];
    const float* e1b    = (const float*)d_in[7];
    const float* e2w    = (const float*)d_in[8];
    const float* e2b    = (const float*)d_in[9];
    const float* root_w = (const float*)d_in[10];
    const float* conv_b = (const float*)d_in[11];
    const float* gru_wi = (const float*)d_in[12];
    const float* gru_wh = (const float*)d_in[13];
    const float* gru_bi = (const float*)d_in[14];
    const float* gru_bh = (const float*)d_in[15];
    const float* lstm_bi = (const float*)d_in[18];
    const float* lstm_bh = (const float*)d_in[19];
    const float* f1w    = (const float*)d_in[20];
    const float* f1b    = (const float*)d_in[21];
    const float* f2w    = (const float*)d_in[22];
    const float* f2b    = (const float*)d_in[23];
    const float* f3w    = (const float*)d_in[24];
    const float* f3b    = (const float*)d_in[25];

    const int N = in_sizes[0] / 4;
    const int E = in_sizes[2];

    float* ws   = (float*)d_ws;
    float* h    = ws;                        // N*32
    float* A    = h + (size_t)N * H;         // N*288 (ping)
    float* Bb   = A + (size_t)N * 288;       // N*288 (pong)
    float* ebuf = Bb + (size_t)N * 288;      // N
    float* qvec = ebuf + N;                  // 32
    unsigned int* segmax = (unsigned int*)(qvec + H);  // 16
    float* ssum = (float*)(segmax + BSEG);   // 16
    float* vsum = ssum + BSEG;               // 512
    float* WI   = vsum + BSEG * H;           // 3072
    float* WH   = WI + 3072;                 // 3072
    float* BS   = WH + 3072;                 // 128
    float* MP   = BS + 128;                  // 1024
    float* MM   = MP + 1024;                 // 1024
    int*   flag = (int*)(MM + 1024);         // 1
    int*   cnt    = flag + 1;                // N
    int*   rowptr = cnt + N;                 // N+1
    int*   cursor = rowptr + N + 1;          // N
    int*   esrc   = cursor + N;              // E
    float* eattr  = (float*)(esrc + E);      // E

    const int nwaves = (N + 7) / 8;          // 8 nodes per wave
    const int nb4 = (nwaves + 3) / 4;        // 4 waves per block
    const int cblocks = (E + 255) / 256;

    k_prep<<<1, 512, 0, stream>>>(gru_wi, gru_wh, gru_bi, gru_bh, lstm_bi, lstm_bh,
                                  e1w, e1b, e2w,
                                  WI, WH, BS, MP, MM, flag, qvec, segmax, ssum, vsum, cnt, N);
    k_count<<<cblocks, 256, 0, stream>>>(ei, cnt, E);
    k_scan<<<1, 1024, 0, stream>>>(cnt, rowptr, cursor, N);
    k_scatter<<<cblocks, 256, 0, stream>>>(ei, ea, cursor, esrc, eattr, E);
    k_tab<<<nb4, 256, 0, stream>>>(x, proj_w, proj_b, e2w, e2b, MP, MM, flag, h, A, N);

    k_gru<<<nb4, 256, 0, stream>>>(h, rowptr, esrc, eattr, A, flag, root_w, conv_b,
                                   WI, WH, BS, MP, MM, e2b, e2w, e1w, e1b, Bb, N, 1);
    k_gru<<<nb4, 256, 0, stream>>>(h, rowptr, esrc, eattr, Bb, flag, root_w, conv_b,
                                   WI, WH, BS, MP, MM, e2b, e2w, e1w, e1b, A, N, 1);
    k_gru<<<nb4, 256, 0, stream>>>(h, rowptr, esrc, eattr, A, flag, root_w, conv_b,
                                   WI, WH, BS, MP, MM, e2b, e2w, e1w, e1b, Bb, N, 0);

    k_pass1<<<BSEG * CHUNKS, 256, 0, stream>>>(h, batch, qvec, ebuf, segmax, N);
    k_pass2<<<BSEG * CHUNKS, 256, 0, stream>>>(h, batch, ebuf, segmax, ssum, vsum, N);
    k_mlp<<<1, 512, 0, stream>>>(qvec, ssum, vsum, f1w, f1b, f2w, f2b, f3w, f3b, (float*)d_out);
}